// Round 1
// baseline (5899.509 us; speedup 1.0000x reference)
//
#include <hip/hip_runtime.h>
#include <math.h>

// Problem constants
constexpr int kB = 64;     // batch
constexpr int kN = 196;    // tokens in X
constexpr int kC = 512;    // X channels
constexpr int kE = 512;    // embedding dim
constexpr int kH = 1024;   // hidden
constexpr int kV = 10000;  // vocab
constexpr int kT = 20;     // steps
constexpr int kG4 = 4 * kH; // 4096

__device__ __forceinline__ float sigmoidf_(float x) { return 1.0f / (1.0f + expf(-x)); }

// ---------------- setup kernels ----------------

// XsT[c][b] = sum_n X[b][n][c]
__global__ __launch_bounds__(256) void k_colsum(const float* __restrict__ X,
                                                float* __restrict__ XsT) {
    int gid = blockIdx.x * 256 + threadIdx.x;      // 64*512
    int b = gid >> 9, c = gid & 511;
    const float* p = X + (size_t)b * kN * kC + c;
    float s = 0.f;
    for (int n = 0; n < kN; ++n) s += p[(size_t)n * kC];
    XsT[c * kB + b] = s;
}

// c0 -> cT[j][b], h0 -> A0[(kE+j)][b]
__global__ __launch_bounds__(256) void k_init(const float* __restrict__ XsT,
                                              const float* __restrict__ Wc0,
                                              const float* __restrict__ bc0,
                                              const float* __restrict__ Wh0,
                                              const float* __restrict__ bh0,
                                              float* __restrict__ cT,
                                              float* __restrict__ A0) {
    int gid = blockIdx.x * 256 + threadIdx.x;      // 1024*64
    int j = gid >> 6, b = gid & 63;
    float ac = 0.f, ah = 0.f;
#pragma unroll 4
    for (int k = 0; k < kC; ++k) {
        float xm = XsT[k * kB + b] * (1.0f / 196.0f);
        ac += xm * Wc0[k * kH + j];
        ah += xm * Wh0[k * kH + j];
    }
    cT[j * kB + b] = tanhf(ac + bc0[j]);
    A0[(kE + j) * kB + b] = tanhf(ah + bh0[j]);
}

// gbT[j][b] = b_ih[j] + b_hh[j] + sum_c Xsum[b][c] * W_ih[512+c][j]
__global__ __launch_bounds__(256) void k_base(const float* __restrict__ XsT,
                                              const float* __restrict__ W_ih,
                                              const float* __restrict__ b_ih,
                                              const float* __restrict__ b_hh,
                                              float* __restrict__ gbT) {
    int gid = blockIdx.x * 256 + threadIdx.x;      // 4096*64
    int j = gid >> 6, b = gid & 63;
    float a = b_ih[j] + b_hh[j];
#pragma unroll 4
    for (int c = 0; c < kC; ++c)
        a += XsT[c * kB + b] * W_ih[(size_t)(kE + c) * kG4 + j];
    gbT[j * kB + b] = a;
}

// ctxT[e][b] = blc[e] + sum_c Xsum[b][c] * Wlc[c][e]
__global__ __launch_bounds__(256) void k_ctxproj(const float* __restrict__ XsT,
                                                 const float* __restrict__ Wlc,
                                                 const float* __restrict__ blc,
                                                 float* __restrict__ ctxT) {
    int gid = blockIdx.x * 256 + threadIdx.x;      // 512*64
    int e = gid >> 6, b = gid & 63;
    float a = blc[e];
#pragma unroll 4
    for (int c = 0; c < kC; ++c)
        a += XsT[c * kB + b] * Wlc[c * kE + e];
    ctxT[e * kB + b] = a;
}

// A0 e-part: emb[START_IDX=1] broadcast to all b
__global__ __launch_bounds__(256) void k_emb0(const float* __restrict__ emb,
                                              float* __restrict__ A0) {
    int gid = blockIdx.x * 256 + threadIdx.x;      // 512*64
    int k = gid >> 6;
    A0[gid] = emb[kE + k];  // row 1
}

// out[:,0,:] = one_hot(1)
__global__ __launch_bounds__(256) void k_out0(float* __restrict__ out) {
    int gid = blockIdx.x * 256 + threadIdx.x;      // 64*10000
    if (gid >= kB * kV) return;
    int b = gid / kV, v = gid - b * kV;
    out[(size_t)b * kT * kV + v] = (v == 1) ? 1.0f : 0.0f;
}

// ---------------- per-step kernels ----------------

// gates GEMM [64 x 1536]·[1536 x 4096] + LSTM elementwise.
// grid 256 blocks; block covers jq-tile of 4 (16 columns incl. 4 gates).
// thread t: b = t&63 (lane), g = t>>6 (gate). acc over 4 consecutive jq.
__global__ __launch_bounds__(256) void k_gates(const float* __restrict__ Ac,
                                               float* __restrict__ An,
                                               float* __restrict__ cT,
                                               const float* __restrict__ gbT,
                                               const float* __restrict__ W_ih,
                                               const float* __restrict__ W_hh) {
    __shared__ float gt[4 * 4 * 64];  // [gate][jq_local][b]
    int t = threadIdx.x;
    int b = t & 63, g = t >> 6;
    int jq0 = blockIdx.x * 4;

    float a0 = 0.f, a1 = 0.f, a2 = 0.f, a3 = 0.f;
    const float* wih = W_ih + g * kH + jq0;
#pragma unroll 4
    for (int k = 0; k < kE; ++k) {
        float a = Ac[k * kB + b];
        float4 w = *reinterpret_cast<const float4*>(wih + (size_t)k * kG4);
        a0 += a * w.x; a1 += a * w.y; a2 += a * w.z; a3 += a * w.w;
    }
    const float* whh = W_hh + g * kH + jq0;
#pragma unroll 4
    for (int k = 0; k < kH; ++k) {
        float a = Ac[(kE + k) * kB + b];
        float4 w = *reinterpret_cast<const float4*>(whh + (size_t)k * kG4);
        a0 += a * w.x; a1 += a * w.y; a2 += a * w.z; a3 += a * w.w;
    }
    gt[(g * 4 + 0) * 64 + b] = a0 + gbT[(g * kH + jq0 + 0) * kB + b];
    gt[(g * 4 + 1) * 64 + b] = a1 + gbT[(g * kH + jq0 + 1) * kB + b];
    gt[(g * 4 + 2) * 64 + b] = a2 + gbT[(g * kH + jq0 + 2) * kB + b];
    gt[(g * 4 + 3) * 64 + b] = a3 + gbT[(g * kH + jq0 + 3) * kB + b];
    __syncthreads();

    // elementwise LSTM: thread handles (b, j = jq0 + q), q = g
    int q = g;
    int j = jq0 + q;
    float gi = gt[(0 * 4 + q) * 64 + b];
    float gf = gt[(1 * 4 + q) * 64 + b];
    float gg = gt[(2 * 4 + q) * 64 + b];
    float go = gt[(3 * 4 + q) * 64 + b];
    float cold = cT[j * kB + b];
    float c2 = sigmoidf_(gf) * cold + sigmoidf_(gi) * tanhf(gg);
    float h2 = sigmoidf_(go) * tanhf(c2);
    cT[j * kB + b] = c2;
    An[(kE + j) * kB + b] = h2;
}

// combT[e][b] = e_tok + ctx_proj + blh + h2 @ Wlh
__global__ __launch_bounds__(256) void k_comb(const float* __restrict__ Ac,
                                              const float* __restrict__ An,
                                              const float* __restrict__ ctxT,
                                              const float* __restrict__ Wlh,
                                              const float* __restrict__ blh,
                                              float* __restrict__ combT) {
    int gid = blockIdx.x * 256 + threadIdx.x;      // 512*64
    int e = gid >> 6, b = gid & 63;
    float a = Ac[e * kB + b] + ctxT[e * kB + b] + blh[e];
#pragma unroll 4
    for (int k = 0; k < kH; ++k)
        a += An[(kE + k) * kB + b] * Wlh[(size_t)k * kE + e];
    combT[e * kB + b] = a;
}

// logitsT[col][b] = bout[col] + comb @ Wout
__global__ __launch_bounds__(256) void k_logits(const float* __restrict__ combT,
                                                const float* __restrict__ Wout,
                                                const float* __restrict__ bout,
                                                float* __restrict__ lT) {
    int t = threadIdx.x;
    int b = t & 63, cg = t >> 6;
    int col0 = blockIdx.x * 16 + cg * 4;
    float a0 = 0.f, a1 = 0.f, a2 = 0.f, a3 = 0.f;
#pragma unroll 4
    for (int k = 0; k < kE; ++k) {
        float a = combT[k * kB + b];
        float4 w = *reinterpret_cast<const float4*>(Wout + (size_t)k * kV + col0);
        a0 += a * w.x; a1 += a * w.y; a2 += a * w.z; a3 += a * w.w;
    }
    lT[(col0 + 0) * kB + b] = a0 + bout[col0 + 0];
    lT[(col0 + 1) * kB + b] = a1 + bout[col0 + 1];
    lT[(col0 + 2) * kB + b] = a2 + bout[col0 + 2];
    lT[(col0 + 3) * kB + b] = a3 + bout[col0 + 3];
}

// per-row (b) log-softmax + argmax + write out row + gather next e into An
__global__ __launch_bounds__(256) void k_finish(const float* __restrict__ lT,
                                                float* __restrict__ out,
                                                const float* __restrict__ emb,
                                                float* __restrict__ An,
                                                int step) {
    __shared__ float smax[256];
    __shared__ int sidx[256];
    __shared__ float ssum[256];
    int b = blockIdx.x;
    int t = threadIdx.x;

    float mx = -3.4e38f; int mi = 0;
    for (int c = t; c < kV; c += 256) {
        float v = lT[c * kB + b];
        if (v > mx) { mx = v; mi = c; }
    }
    smax[t] = mx; sidx[t] = mi;
    __syncthreads();
    for (int s = 128; s > 0; s >>= 1) {
        if (t < s) {
            float v2 = smax[t + s]; int i2 = sidx[t + s];
            if (v2 > smax[t] || (v2 == smax[t] && i2 < sidx[t])) { smax[t] = v2; sidx[t] = i2; }
        }
        __syncthreads();
    }
    mx = smax[0]; mi = sidx[0];

    float s = 0.f;
    for (int c = t; c < kV; c += 256) s += expf(lT[c * kB + b] - mx);
    ssum[t] = s;
    __syncthreads();
    for (int ss = 128; ss > 0; ss >>= 1) {
        if (t < ss) ssum[t] += ssum[t + ss];
        __syncthreads();
    }
    float lse = mx + logf(ssum[0]);

    float* orow = out + (size_t)b * kT * kV + (size_t)step * kV;
    for (int c = t; c < kV; c += 256) orow[c] = lT[c * kB + b] - lse;

    // gather next-step embedding (argmax token) into An e-part
    for (int k = t; k < kE; k += 256) An[k * kB + b] = emb[(size_t)mi * kE + k];
}

// ---------------- launcher ----------------

extern "C" void kernel_launch(void* const* d_in, const int* in_sizes, int n_in,
                              void* d_out, int out_size, void* d_ws, size_t ws_size,
                              hipStream_t stream) {
    const float* X    = (const float*)d_in[0];
    const float* emb  = (const float*)d_in[1];
    const float* W_ih = (const float*)d_in[2];
    const float* b_ih = (const float*)d_in[3];
    const float* W_hh = (const float*)d_in[4];
    const float* b_hh = (const float*)d_in[5];
    // d_in[6..11]: Wa, ba, Wh, bh, Wo, bo — dead (softmax over size-1 axis => weights==1)
    const float* Wlh  = (const float*)d_in[12];
    const float* blh  = (const float*)d_in[13];
    const float* Wlc  = (const float*)d_in[14];
    const float* blc  = (const float*)d_in[15];
    const float* Wout = (const float*)d_in[16];
    const float* bout = (const float*)d_in[17];
    const float* Wc0  = (const float*)d_in[18];
    const float* bc0  = (const float*)d_in[19];
    const float* Wh0  = (const float*)d_in[20];
    const float* bh0  = (const float*)d_in[21];
    float* out = (float*)d_out;

    float* ws = (float*)d_ws;
    float* A0   = ws;                 // 1536*64
    float* A1   = A0 + 1536 * 64;     // 1536*64
    float* cT   = A1 + 1536 * 64;     // 1024*64
    float* gbT  = cT + 1024 * 64;     // 4096*64
    float* ctxT = gbT + 4096 * 64;    // 512*64
    float* combT= ctxT + 512 * 64;    // 512*64
    float* lT   = combT + 512 * 64;   // 10000*64
    float* XsT  = lT + 10000 * 64;    // 512*64

    k_colsum<<<(kB * kC) / 256, 256, 0, stream>>>(X, XsT);
    k_init<<<(kB * kH) / 256, 256, 0, stream>>>(XsT, Wc0, bc0, Wh0, bh0, cT, A0);
    k_base<<<(kG4 * kB) / 256, 256, 0, stream>>>(XsT, W_ih, b_ih, b_hh, gbT);
    k_ctxproj<<<(kE * kB) / 256, 256, 0, stream>>>(XsT, Wlc, blc, ctxT);
    k_emb0<<<(kE * kB) / 256, 256, 0, stream>>>(emb, A0);
    k_out0<<<(kB * kV + 255) / 256, 256, 0, stream>>>(out);

    float* A[2] = {A0, A1};
    for (int s = 1; s < kT; ++s) {
        const float* Ac = A[(s - 1) & 1];
        float* An = A[s & 1];
        k_gates<<<kH / 4, 256, 0, stream>>>(Ac, An, cT, gbT, W_ih, W_hh);
        k_comb<<<(kE * kB) / 256, 256, 0, stream>>>(Ac, An, ctxT, Wlh, blh, combT);
        k_logits<<<kV / 16, 256, 0, stream>>>(combT, Wout, bout, lT);
        k_finish<<<kB, 256, 0, stream>>>(lT, out, emb, An, s);
    }
}

// Round 2
// 3119.005 us; speedup vs baseline: 1.8915x; 1.8915x over previous
//
#include <hip/hip_runtime.h>
#include <math.h>

// Problem constants
constexpr int kB = 64;     // batch
constexpr int kN = 196;    // tokens in X
constexpr int kC = 512;    // X channels
constexpr int kE = 512;    // embedding dim
constexpr int kH = 1024;   // hidden
constexpr int kV = 10000;  // vocab
constexpr int kT = 20;     // steps
constexpr int kG4 = 4 * kH; // 4096
constexpr int kKS_G = 4;   // split-K chunks for gates GEMM (K=1536 -> 384 each)
constexpr int kKS_C = 8;   // split-K chunks for comb GEMM  (K=1024 -> 128 each)

__device__ __forceinline__ float sigmoidf_(float x) { return 1.0f / (1.0f + expf(-x)); }

// ---------------- setup kernels ----------------

// XsT[c][b] = sum_n X[b][n][c]   (ctx is SUM over n: softmax over size-1 axis -> w==1)
__global__ __launch_bounds__(256) void k_colsum(const float* __restrict__ X,
                                                float* __restrict__ XsT) {
    int gid = blockIdx.x * 256 + threadIdx.x;      // 64*512
    int b = gid >> 9, c = gid & 511;
    const float* p = X + (size_t)b * kN * kC + c;
    float s = 0.f;
    for (int n = 0; n < kN; ++n) s += p[(size_t)n * kC];
    XsT[c * kB + b] = s;
}

// c0 = tanh(Xmean@Wc0+bc0) -> cT ; h0 = tanh(Xmean@Wh0+bh0) -> A0 h-part
// grid 128: blocks 0..63 -> Wc0/cT, 64..127 -> Wh0/A0
__global__ __launch_bounds__(256) void k_init2(const float* __restrict__ XsT,
                                               const float* __restrict__ Wc0,
                                               const float* __restrict__ bc0,
                                               const float* __restrict__ Wh0,
                                               const float* __restrict__ bh0,
                                               float* __restrict__ cT,
                                               float* __restrict__ A0) {
    int t = threadIdx.x;
    int b = t & 63, q = t >> 6;
    int m = blockIdx.x >> 6;                   // 0: cell, 1: hidden
    int j = (blockIdx.x & 63) * 16 + q * 4;
    const float* W  = m ? Wh0 : Wc0;
    const float* bi = m ? bh0 : bc0;
    float a0 = 0.f, a1 = 0.f, a2 = 0.f, a3 = 0.f;
#pragma unroll 4
    for (int k = 0; k < kC; ++k) {
        float4 w = *reinterpret_cast<const float4*>(W + (size_t)k * kH + j);
        float a = XsT[k * kB + b] * (1.0f / 196.0f);
        a0 += a * w.x; a1 += a * w.y; a2 += a * w.z; a3 += a * w.w;
    }
    float* dst = m ? (A0 + (size_t)kE * kB) : cT;
    dst[(j + 0) * kB + b] = tanhf(a0 + bi[j + 0]);
    dst[(j + 1) * kB + b] = tanhf(a1 + bi[j + 1]);
    dst[(j + 2) * kB + b] = tanhf(a2 + bi[j + 2]);
    dst[(j + 3) * kB + b] = tanhf(a3 + bi[j + 3]);
}

// gbT[j][b] = b_ih[j] + b_hh[j] + sum_c Xsum[b][c] * W_ih[512+c][j]   (grid 256)
__global__ __launch_bounds__(256) void k_base2(const float* __restrict__ XsT,
                                               const float* __restrict__ W_ih,
                                               const float* __restrict__ b_ih,
                                               const float* __restrict__ b_hh,
                                               float* __restrict__ gbT) {
    int t = threadIdx.x;
    int b = t & 63, q = t >> 6;
    int j = blockIdx.x * 16 + q * 4;
    float a0 = 0.f, a1 = 0.f, a2 = 0.f, a3 = 0.f;
#pragma unroll 4
    for (int k = 0; k < kC; ++k) {
        float4 w = *reinterpret_cast<const float4*>(W_ih + (size_t)(kE + k) * kG4 + j);
        float a = XsT[k * kB + b];
        a0 += a * w.x; a1 += a * w.y; a2 += a * w.z; a3 += a * w.w;
    }
    float* p = gbT + (size_t)j * kB + b;
    p[0]   = a0 + b_ih[j + 0] + b_hh[j + 0];
    p[64]  = a1 + b_ih[j + 1] + b_hh[j + 1];
    p[128] = a2 + b_ih[j + 2] + b_hh[j + 2];
    p[192] = a3 + b_ih[j + 3] + b_hh[j + 3];
}

// ctxT[e][b] = blc[e] + sum_c Xsum[b][c] * Wlc[c][e]   (grid 32)
__global__ __launch_bounds__(256) void k_ctx2(const float* __restrict__ XsT,
                                              const float* __restrict__ Wlc,
                                              const float* __restrict__ blc,
                                              float* __restrict__ ctxT) {
    int t = threadIdx.x;
    int b = t & 63, q = t >> 6;
    int j = blockIdx.x * 16 + q * 4;
    float a0 = 0.f, a1 = 0.f, a2 = 0.f, a3 = 0.f;
#pragma unroll 4
    for (int k = 0; k < kC; ++k) {
        float4 w = *reinterpret_cast<const float4*>(Wlc + (size_t)k * kE + j);
        float a = XsT[k * kB + b];
        a0 += a * w.x; a1 += a * w.y; a2 += a * w.z; a3 += a * w.w;
    }
    float* p = ctxT + (size_t)j * kB + b;
    p[0] = a0 + blc[j + 0]; p[64] = a1 + blc[j + 1];
    p[128] = a2 + blc[j + 2]; p[192] = a3 + blc[j + 3];
}

// A0 e-part: emb[START_IDX=1] broadcast to all b
__global__ __launch_bounds__(256) void k_emb0(const float* __restrict__ emb,
                                              float* __restrict__ A0) {
    int gid = blockIdx.x * 256 + threadIdx.x;      // 512*64
    int k = gid >> 6;
    A0[gid] = emb[kE + k];  // row 1
}

// out[:,0,:] = one_hot(1)
__global__ __launch_bounds__(256) void k_out0(float* __restrict__ out) {
    int gid = blockIdx.x * 256 + threadIdx.x;      // 64*10000
    if (gid >= kB * kV) return;
    int b = gid / kV, v = gid - b * kV;
    out[(size_t)b * kT * kV + v] = (v == 1) ? 1.0f : 0.0f;
}

// ---------------- per-step kernels ----------------

// gates partial GEMM: P[kc][j][b] = sum_{k in chunk kc} A[k][b] * W(k)[j]
// A rows 0..511 = e (W_ih rows 0..511), rows 512..1535 = h (W_hh).
// grid 1024 = 256 col-tiles x 4 k-chunks. 16 consecutive cols per block.
__global__ __launch_bounds__(256) void k_gates(const float* __restrict__ A,
                                               const float* __restrict__ W_ih,
                                               const float* __restrict__ W_hh,
                                               float* __restrict__ P) {
    int t = threadIdx.x;
    int b = t & 63, q = t >> 6;
    int jt = blockIdx.x & 255;
    int kc = blockIdx.x >> 8;
    int j = jt * 16 + q * 4;
    int k0 = kc * 384;
    float a0 = 0.f, a1 = 0.f, a2 = 0.f, a3 = 0.f;
#pragma unroll 4
    for (int k = k0; k < k0 + 384; ++k) {
        const float* wrow = (k < kE) ? (W_ih + (size_t)k * kG4)
                                     : (W_hh + (size_t)(k - kE) * kG4);
        float4 w = *reinterpret_cast<const float4*>(wrow + j);
        float a = A[k * kB + b];
        a0 += a * w.x; a1 += a * w.y; a2 += a * w.z; a3 += a * w.w;
    }
    float* p = P + (size_t)kc * kG4 * kB + (size_t)j * kB + b;
    p[0] = a0; p[64] = a1; p[128] = a2; p[192] = a3;
}

// reduce partials + gbT, apply LSTM nonlinearity. grid 256 (j-tile of 4).
__global__ __launch_bounds__(256) void k_lstm(const float* __restrict__ P,
                                              const float* __restrict__ gbT,
                                              float* __restrict__ cT,
                                              float* __restrict__ An) {
    int t = threadIdx.x;
    int b = t & 63, q = t >> 6;
    int j = blockIdx.x * 4 + q;
    float g[4];
#pragma unroll
    for (int gi = 0; gi < 4; ++gi) {
        int row = gi * kH + j;
        float s = gbT[(size_t)row * kB + b];
#pragma unroll
        for (int kc = 0; kc < kKS_G; ++kc)
            s += P[(size_t)kc * kG4 * kB + (size_t)row * kB + b];
        g[gi] = s;
    }
    float c2 = sigmoidf_(g[1]) * cT[j * kB + b] + sigmoidf_(g[0]) * tanhf(g[2]);
    float h2 = sigmoidf_(g[3]) * tanhf(c2);
    cT[j * kB + b] = c2;
    An[(size_t)(kE + j) * kB + b] = h2;
}

// comb partial GEMM: P2[kc][e][b] = sum_{k in chunk} h[k][b] * Wlh[k][e]
// grid 256 = 32 col-tiles x 8 k-chunks
__global__ __launch_bounds__(256) void k_comb(const float* __restrict__ An,
                                              const float* __restrict__ Wlh,
                                              float* __restrict__ P2) {
    int t = threadIdx.x;
    int b = t & 63, q = t >> 6;
    int jt = blockIdx.x & 31;
    int kc = blockIdx.x >> 5;
    int j = jt * 16 + q * 4;
    int k0 = kc * 128;
    float a0 = 0.f, a1 = 0.f, a2 = 0.f, a3 = 0.f;
#pragma unroll 4
    for (int k = k0; k < k0 + 128; ++k) {
        float4 w = *reinterpret_cast<const float4*>(Wlh + (size_t)k * kE + j);
        float a = An[(size_t)(kE + k) * kB + b];
        a0 += a * w.x; a1 += a * w.y; a2 += a * w.z; a3 += a * w.w;
    }
    float* p = P2 + (size_t)kc * kE * kB + (size_t)j * kB + b;
    p[0] = a0; p[64] = a1; p[128] = a2; p[192] = a3;
}

// combT = e + ctx_proj + blh + sum partials. grid 128.
__global__ __launch_bounds__(256) void k_combred(const float* __restrict__ P2,
                                                 const float* __restrict__ Ac,
                                                 const float* __restrict__ ctxT,
                                                 const float* __restrict__ blh,
                                                 float* __restrict__ combT) {
    int gid = blockIdx.x * 256 + threadIdx.x;     // 512*64
    int e = gid >> 6;
    float s = Ac[gid] + ctxT[gid] + blh[e];
#pragma unroll
    for (int kc = 0; kc < kKS_C; ++kc)
        s += P2[(size_t)kc * kE * kB + gid];
    combT[gid] = s;
}

// logits: lT[j][b] = bout[j] + sum_k comb[k][b]*Wout[k][j]. grid 625 (10000/16).
__global__ __launch_bounds__(256) void k_logits(const float* __restrict__ combT,
                                                const float* __restrict__ Wout,
                                                const float* __restrict__ bout,
                                                float* __restrict__ lT) {
    int t = threadIdx.x;
    int b = t & 63, q = t >> 6;
    int j = blockIdx.x * 16 + q * 4;
    float a0 = 0.f, a1 = 0.f, a2 = 0.f, a3 = 0.f;
#pragma unroll 4
    for (int k = 0; k < kE; ++k) {
        float4 w = *reinterpret_cast<const float4*>(Wout + (size_t)k * kV + j);
        float a = combT[k * kB + b];
        a0 += a * w.x; a1 += a * w.y; a2 += a * w.z; a3 += a * w.w;
    }
    float* p = lT + (size_t)j * kB + b;
    p[0]   = a0 + bout[j + 0];
    p[64]  = a1 + bout[j + 1];
    p[128] = a2 + bout[j + 2];
    p[192] = a3 + bout[j + 3];
}

// per-row (b) log-softmax + argmax + write out row + gather next e into An
__global__ __launch_bounds__(256) void k_finish(const float* __restrict__ lT,
                                                float* __restrict__ out,
                                                const float* __restrict__ emb,
                                                float* __restrict__ An,
                                                int step) {
    __shared__ float smax[256];
    __shared__ int sidx[256];
    __shared__ float ssum[256];
    int b = blockIdx.x;
    int t = threadIdx.x;

    float mx = -3.4e38f; int mi = 0;
    for (int c = t; c < kV; c += 256) {
        float v = lT[c * kB + b];
        if (v > mx) { mx = v; mi = c; }
    }
    smax[t] = mx; sidx[t] = mi;
    __syncthreads();
    for (int s = 128; s > 0; s >>= 1) {
        if (t < s) {
            float v2 = smax[t + s]; int i2 = sidx[t + s];
            if (v2 > smax[t] || (v2 == smax[t] && i2 < sidx[t])) { smax[t] = v2; sidx[t] = i2; }
        }
        __syncthreads();
    }
    mx = smax[0]; mi = sidx[0];

    float s = 0.f;
    for (int c = t; c < kV; c += 256) s += expf(lT[c * kB + b] - mx);
    ssum[t] = s;
    __syncthreads();
    for (int ss = 128; ss > 0; ss >>= 1) {
        if (t < ss) ssum[t] += ssum[t + ss];
        __syncthreads();
    }
    float lse = mx + logf(ssum[0]);

    float* orow = out + (size_t)b * kT * kV + (size_t)step * kV;
    for (int c = t; c < kV; c += 256) orow[c] = lT[c * kB + b] - lse;

    for (int k = t; k < kE; k += 256) An[k * kB + b] = emb[(size_t)mi * kE + k];
}

// ---------------- launcher ----------------

extern "C" void kernel_launch(void* const* d_in, const int* in_sizes, int n_in,
                              void* d_out, int out_size, void* d_ws, size_t ws_size,
                              hipStream_t stream) {
    const float* X    = (const float*)d_in[0];
    const float* emb  = (const float*)d_in[1];
    const float* W_ih = (const float*)d_in[2];
    const float* b_ih = (const float*)d_in[3];
    const float* W_hh = (const float*)d_in[4];
    const float* b_hh = (const float*)d_in[5];
    // d_in[6..11]: Wa, ba, Wh, bh, Wo, bo — dead (softmax over size-1 axis => weights==1)
    const float* Wlh  = (const float*)d_in[12];
    const float* blh  = (const float*)d_in[13];
    const float* Wlc  = (const float*)d_in[14];
    const float* blc  = (const float*)d_in[15];
    const float* Wout = (const float*)d_in[16];
    const float* bout = (const float*)d_in[17];
    const float* Wc0  = (const float*)d_in[18];
    const float* bc0  = (const float*)d_in[19];
    const float* Wh0  = (const float*)d_in[20];
    const float* bh0  = (const float*)d_in[21];
    float* out = (float*)d_out;

    float* ws = (float*)d_ws;
    float* A0    = ws;                    // 1536*64
    float* A1    = A0   + 1536 * 64;      // 1536*64
    float* cT    = A1   + 1536 * 64;      // 1024*64
    float* gbT   = cT   + 1024 * 64;      // 4096*64
    float* ctxT  = gbT  + 4096 * 64;      // 512*64
    float* combT = ctxT + 512 * 64;       // 512*64
    float* lT    = combT+ 512 * 64;       // 10000*64
    float* XsT   = lT   + 10000 * 64;     // 512*64
    float* P     = XsT  + 512 * 64;       // 4*4096*64
    float* P2    = P    + kKS_G * kG4 * kB; // 8*512*64

    k_colsum<<<(kB * kC) / 256, 256, 0, stream>>>(X, XsT);
    k_init2<<<128, 256, 0, stream>>>(XsT, Wc0, bc0, Wh0, bh0, cT, A0);
    k_base2<<<kG4 / 16, 256, 0, stream>>>(XsT, W_ih, b_ih, b_hh, gbT);
    k_ctx2<<<kE / 16, 256, 0, stream>>>(XsT, Wlc, blc, ctxT);
    k_emb0<<<(kE * kB) / 256, 256, 0, stream>>>(emb, A0);
    k_out0<<<(kB * kV + 255) / 256, 256, 0, stream>>>(out);

    float* A[2] = {A0, A1};
    for (int s = 1; s < kT; ++s) {
        const float* Ac = A[(s - 1) & 1];
        float* An = A[s & 1];
        k_gates<<<(kG4 / 16) * kKS_G, 256, 0, stream>>>(Ac, W_ih, W_hh, P);
        k_lstm<<<kH / 4, 256, 0, stream>>>(P, gbT, cT, An);
        k_comb<<<(kE / 16) * kKS_C, 256, 0, stream>>>(An, Wlh, P2);
        k_combred<<<(kE * kB) / 256, 256, 0, stream>>>(P2, Ac, ctxT, blh, combT);
        k_logits<<<kV / 16, 256, 0, stream>>>(combT, Wout, bout, lT);
        k_finish<<<kB, 256, 0, stream>>>(lT, out, emb, An, s);
    }
}

// Round 3
// 1710.022 us; speedup vs baseline: 3.4500x; 1.8240x over previous
//
#include <hip/hip_runtime.h>
#include <math.h>

// Problem constants
constexpr int kB = 64;     // batch
constexpr int kN = 196;    // tokens in X
constexpr int kC = 512;    // X channels
constexpr int kE = 512;    // embedding dim
constexpr int kH = 1024;   // hidden
constexpr int kV = 10000;  // vocab
constexpr int kT = 20;     // steps
constexpr int kG4 = 4 * kH; // 4096
constexpr int kKS_G = 8;   // split-K chunks for gates GEMM (K=1536 -> 192 each)
constexpr int kKS_C = 16;  // split-K chunks for comb GEMM  (K=1024 -> 64 each)
constexpr int kKS_L = 4;   // split-K chunks for logits GEMM (K=512 -> 128 each)

__device__ __forceinline__ float sigmoidf_(float x) { return 1.0f / (1.0f + expf(-x)); }

// ---------------- setup kernels (run once; not perf-critical) ----------------

// XsT[c][b] = sum_n X[b][n][c]   (ctx: softmax over size-1 axis -> weights==1)
__global__ __launch_bounds__(256) void k_colsum(const float* __restrict__ X,
                                                float* __restrict__ XsT) {
    int gid = blockIdx.x * 256 + threadIdx.x;      // 64*512
    int b = gid >> 9, c = gid & 511;
    const float* p = X + (size_t)b * kN * kC + c;
    float s = 0.f;
    for (int n = 0; n < kN; ++n) s += p[(size_t)n * kC];
    XsT[c * kB + b] = s;
}

__global__ __launch_bounds__(256) void k_init2(const float* __restrict__ XsT,
                                               const float* __restrict__ Wc0,
                                               const float* __restrict__ bc0,
                                               const float* __restrict__ Wh0,
                                               const float* __restrict__ bh0,
                                               float* __restrict__ cT,
                                               float* __restrict__ A0) {
    int t = threadIdx.x;
    int b = t & 63, q = t >> 6;
    int m = blockIdx.x >> 6;                   // 0: cell, 1: hidden
    int j = (blockIdx.x & 63) * 16 + q * 4;
    const float* W  = m ? Wh0 : Wc0;
    const float* bi = m ? bh0 : bc0;
    float a0 = 0.f, a1 = 0.f, a2 = 0.f, a3 = 0.f;
#pragma unroll 4
    for (int k = 0; k < kC; ++k) {
        float4 w = *reinterpret_cast<const float4*>(W + (size_t)k * kH + j);
        float a = XsT[k * kB + b] * (1.0f / 196.0f);
        a0 += a * w.x; a1 += a * w.y; a2 += a * w.z; a3 += a * w.w;
    }
    float* dst = m ? (A0 + (size_t)kE * kB) : cT;
    dst[(j + 0) * kB + b] = tanhf(a0 + bi[j + 0]);
    dst[(j + 1) * kB + b] = tanhf(a1 + bi[j + 1]);
    dst[(j + 2) * kB + b] = tanhf(a2 + bi[j + 2]);
    dst[(j + 3) * kB + b] = tanhf(a3 + bi[j + 3]);
}

__global__ __launch_bounds__(256) void k_base2(const float* __restrict__ XsT,
                                               const float* __restrict__ W_ih,
                                               const float* __restrict__ b_ih,
                                               const float* __restrict__ b_hh,
                                               float* __restrict__ gbT) {
    int t = threadIdx.x;
    int b = t & 63, q = t >> 6;
    int j = blockIdx.x * 16 + q * 4;
    float a0 = 0.f, a1 = 0.f, a2 = 0.f, a3 = 0.f;
#pragma unroll 4
    for (int k = 0; k < kC; ++k) {
        float4 w = *reinterpret_cast<const float4*>(W_ih + (size_t)(kE + k) * kG4 + j);
        float a = XsT[k * kB + b];
        a0 += a * w.x; a1 += a * w.y; a2 += a * w.z; a3 += a * w.w;
    }
    float* p = gbT + (size_t)j * kB + b;
    p[0]   = a0 + b_ih[j + 0] + b_hh[j + 0];
    p[64]  = a1 + b_ih[j + 1] + b_hh[j + 1];
    p[128] = a2 + b_ih[j + 2] + b_hh[j + 2];
    p[192] = a3 + b_ih[j + 3] + b_hh[j + 3];
}

__global__ __launch_bounds__(256) void k_ctx2(const float* __restrict__ XsT,
                                              const float* __restrict__ Wlc,
                                              const float* __restrict__ blc,
                                              float* __restrict__ ctxT) {
    int t = threadIdx.x;
    int b = t & 63, q = t >> 6;
    int j = blockIdx.x * 16 + q * 4;
    float a0 = 0.f, a1 = 0.f, a2 = 0.f, a3 = 0.f;
#pragma unroll 4
    for (int k = 0; k < kC; ++k) {
        float4 w = *reinterpret_cast<const float4*>(Wlc + (size_t)k * kE + j);
        float a = XsT[k * kB + b];
        a0 += a * w.x; a1 += a * w.y; a2 += a * w.z; a3 += a * w.w;
    }
    float* p = ctxT + (size_t)j * kB + b;
    p[0] = a0 + blc[j + 0]; p[64] = a1 + blc[j + 1];
    p[128] = a2 + blc[j + 2]; p[192] = a3 + blc[j + 3];
}

__global__ __launch_bounds__(256) void k_emb0(const float* __restrict__ emb,
                                              float* __restrict__ A0) {
    int gid = blockIdx.x * 256 + threadIdx.x;      // 512*64
    int k = gid >> 6;
    A0[gid] = emb[kE + k];  // row START_IDX=1
}

__global__ __launch_bounds__(256) void k_out0(float* __restrict__ out) {
    int gid = blockIdx.x * 256 + threadIdx.x;      // 64*10000
    if (gid >= kB * kV) return;
    int b = gid / kV, v = gid - b * kV;
    out[(size_t)b * kT * kV + v] = (v == 1) ? 1.0f : 0.0f;
}

// ---------------- per-step kernels ----------------

// gates partial GEMM, LDS-staged weight tiles.
// grid 2048 = 256 col-tiles (16 cols) x 8 k-chunks (192 rows each, 3 tiles of 64)
__global__ __launch_bounds__(256) void k_gates(const float* __restrict__ A,
                                               const float* __restrict__ W_ih,
                                               const float* __restrict__ W_hh,
                                               float* __restrict__ P) {
    __shared__ float4 wt[64][4];   // 4 KB weight tile [k_local][col_quad]
    int t = threadIdx.x;
    int b = t & 63, q = t >> 6;
    int jt = blockIdx.x & 255;
    int kc = blockIdx.x >> 8;
    int j = jt * 16;
    int k0 = kc * 192;
    int lr = t >> 2, lq = t & 3;   // staging: row 0..63, quad 0..3

    float a0 = 0.f, a1 = 0.f, a2 = 0.f, a3 = 0.f;
    for (int kt = 0; kt < 192; kt += 64) {
        int k = k0 + kt + lr;
        const float* wrow = (k < kE) ? (W_ih + (size_t)k * kG4)
                                     : (W_hh + (size_t)(k - kE) * kG4);
        float4 w = *reinterpret_cast<const float4*>(wrow + j + lq * 4);  // issued early
        __syncthreads();           // previous tile fully consumed
        wt[lr][lq] = w;
        __syncthreads();
        const float* ap = A + (size_t)(k0 + kt) * kB + b;
#pragma unroll 8
        for (int kk = 0; kk < 64; ++kk) {
            float a = ap[kk * 64];
            float4 ww = wt[kk][q];
            a0 += a * ww.x; a1 += a * ww.y; a2 += a * ww.z; a3 += a * ww.w;
        }
    }
    float* p = P + ((size_t)kc * kG4 + j + q * 4) * kB + b;
    p[0] = a0; p[64] = a1; p[128] = a2; p[192] = a3;
}

// reduce partials + gbT, apply LSTM nonlinearity. grid 256.
__global__ __launch_bounds__(256) void k_lstm(const float* __restrict__ P,
                                              const float* __restrict__ gbT,
                                              float* __restrict__ cT,
                                              float* __restrict__ An) {
    int t = threadIdx.x;
    int b = t & 63, q = t >> 6;
    int j = blockIdx.x * 4 + q;
    float g[4];
#pragma unroll
    for (int gi = 0; gi < 4; ++gi) {
        int row = gi * kH + j;
        float s = gbT[(size_t)row * kB + b];
#pragma unroll
        for (int kc = 0; kc < kKS_G; ++kc)
            s += P[(size_t)kc * kG4 * kB + (size_t)row * kB + b];
        g[gi] = s;
    }
    float c2 = sigmoidf_(g[1]) * cT[j * kB + b] + sigmoidf_(g[0]) * tanhf(g[2]);
    float h2 = sigmoidf_(g[3]) * tanhf(c2);
    cT[j * kB + b] = c2;
    An[(size_t)(kE + j) * kB + b] = h2;
}

// comb partial GEMM. grid 512 = 32 col-tiles x 16 k-chunks (64 rows = 1 tile)
__global__ __launch_bounds__(256) void k_comb(const float* __restrict__ An,
                                              const float* __restrict__ Wlh,
                                              float* __restrict__ P2) {
    __shared__ float4 wt[64][4];
    int t = threadIdx.x;
    int b = t & 63, q = t >> 6;
    int jt = blockIdx.x & 31;
    int kc = blockIdx.x >> 5;
    int j = jt * 16;
    int k0 = kc * 64;
    int lr = t >> 2, lq = t & 3;

    float4 w = *reinterpret_cast<const float4*>(Wlh + (size_t)(k0 + lr) * kE + j + lq * 4);
    wt[lr][lq] = w;
    __syncthreads();
    float a0 = 0.f, a1 = 0.f, a2 = 0.f, a3 = 0.f;
    const float* ap = An + (size_t)(kE + k0) * kB + b;
#pragma unroll 8
    for (int kk = 0; kk < 64; ++kk) {
        float a = ap[kk * 64];
        float4 ww = wt[kk][q];
        a0 += a * ww.x; a1 += a * ww.y; a2 += a * ww.z; a3 += a * ww.w;
    }
    float* p = P2 + ((size_t)kc * kE + j + q * 4) * kB + b;
    p[0] = a0; p[64] = a1; p[128] = a2; p[192] = a3;
}

// combT = e + ctx_proj + blh + sum partials. grid 128.
__global__ __launch_bounds__(256) void k_combred(const float* __restrict__ P2,
                                                 const float* __restrict__ Ac,
                                                 const float* __restrict__ ctxT,
                                                 const float* __restrict__ blh,
                                                 float* __restrict__ combT) {
    int gid = blockIdx.x * 256 + threadIdx.x;     // 512*64
    int e = gid >> 6;
    float s = Ac[gid] + ctxT[gid] + blh[e];
#pragma unroll
    for (int kc = 0; kc < kKS_C; ++kc)
        s += P2[(size_t)kc * kE * kB + gid];
    combT[gid] = s;
}

// logits partial GEMM: Pl[kc][b][c]. grid 2500 = 625 col-tiles x 4 k-chunks (128 = 2 tiles)
__global__ __launch_bounds__(256) void k_logits(const float* __restrict__ combT,
                                                const float* __restrict__ Wout,
                                                float* __restrict__ Pl) {
    __shared__ float4 wt[64][4];
    int t = threadIdx.x;
    int b = t & 63, q = t >> 6;
    int jt = blockIdx.x % 625;
    int kc = blockIdx.x / 625;
    int j = jt * 16;
    int k0 = kc * 128;
    int lr = t >> 2, lq = t & 3;

    float a0 = 0.f, a1 = 0.f, a2 = 0.f, a3 = 0.f;
    for (int kt = 0; kt < 128; kt += 64) {
        int k = k0 + kt + lr;
        float4 w = *reinterpret_cast<const float4*>(Wout + (size_t)k * kV + j + lq * 4);
        __syncthreads();
        wt[lr][lq] = w;
        __syncthreads();
        const float* ap = combT + (size_t)(k0 + kt) * kB + b;
#pragma unroll 8
        for (int kk = 0; kk < 64; ++kk) {
            float a = ap[kk * 64];
            float4 ww = wt[kk][q];
            a0 += a * ww.x; a1 += a * ww.y; a2 += a * ww.z; a3 += a * ww.w;
        }
    }
    float* p = Pl + ((size_t)kc * kB + b) * kV + j + q * 4;
    *reinterpret_cast<float4*>(p) = make_float4(a0, a1, a2, a3);
}

// l[b][c] = bout[c] + sum_kc Pl[kc][b][c]. grid 2500.
__global__ __launch_bounds__(256) void k_lred(const float* __restrict__ Pl,
                                              const float* __restrict__ bout,
                                              float* __restrict__ l) {
    int gid = blockIdx.x * 256 + threadIdx.x;    // 64*10000
    int b = gid / kV, c = gid - b * kV;
    float s = bout[c];
#pragma unroll
    for (int kc = 0; kc < kKS_L; ++kc)
        s += Pl[((size_t)kc * kB + b) * kV + c];
    l[gid] = s;
}

// per-row log-softmax + argmax + out write + next-step embedding gather. grid 64.
__global__ __launch_bounds__(256) void k_finish(const float* __restrict__ l,
                                                float* __restrict__ out,
                                                const float* __restrict__ emb,
                                                float* __restrict__ An,
                                                int step) {
    __shared__ float smax[256];
    __shared__ int sidx[256];
    __shared__ float ssum[256];
    int b = blockIdx.x;
    int t = threadIdx.x;
    const float* lb = l + (size_t)b * kV;

    float mx = -3.4e38f; int mi = 0;
    for (int c = t; c < kV; c += 256) {
        float v = lb[c];
        if (v > mx) { mx = v; mi = c; }
    }
    smax[t] = mx; sidx[t] = mi;
    __syncthreads();
    for (int s = 128; s > 0; s >>= 1) {
        if (t < s) {
            float v2 = smax[t + s]; int i2 = sidx[t + s];
            if (v2 > smax[t] || (v2 == smax[t] && i2 < sidx[t])) { smax[t] = v2; sidx[t] = i2; }
        }
        __syncthreads();
    }
    mx = smax[0]; mi = sidx[0];

    float s = 0.f;
    for (int c = t; c < kV; c += 256) s += expf(lb[c] - mx);
    ssum[t] = s;
    __syncthreads();
    for (int ss = 128; ss > 0; ss >>= 1) {
        if (t < ss) ssum[t] += ssum[t + ss];
        __syncthreads();
    }
    float lse = mx + logf(ssum[0]);

    float* orow = out + (size_t)b * kT * kV + (size_t)step * kV;
    for (int c = t; c < kV; c += 256) orow[c] = lb[c] - lse;

    for (int k = t; k < kE; k += 256) An[k * kB + b] = emb[(size_t)mi * kE + k];
}

// ---------------- launcher ----------------

extern "C" void kernel_launch(void* const* d_in, const int* in_sizes, int n_in,
                              void* d_out, int out_size, void* d_ws, size_t ws_size,
                              hipStream_t stream) {
    const float* X    = (const float*)d_in[0];
    const float* emb  = (const float*)d_in[1];
    const float* W_ih = (const float*)d_in[2];
    const float* b_ih = (const float*)d_in[3];
    const float* W_hh = (const float*)d_in[4];
    const float* b_hh = (const float*)d_in[5];
    // d_in[6..11]: Wa, ba, Wh, bh, Wo, bo — dead (softmax over size-1 axis => weights==1)
    const float* Wlh  = (const float*)d_in[12];
    const float* blh  = (const float*)d_in[13];
    const float* Wlc  = (const float*)d_in[14];
    const float* blc  = (const float*)d_in[15];
    const float* Wout = (const float*)d_in[16];
    const float* bout = (const float*)d_in[17];
    const float* Wc0  = (const float*)d_in[18];
    const float* bc0  = (const float*)d_in[19];
    const float* Wh0  = (const float*)d_in[20];
    const float* bh0  = (const float*)d_in[21];
    float* out = (float*)d_out;

    float* ws = (float*)d_ws;
    float* A0    = ws;                        // 1536*64
    float* A1    = A0   + 1536 * 64;          // 1536*64
    float* cT    = A1   + 1536 * 64;          // 1024*64
    float* gbT   = cT   + 1024 * 64;          // 4096*64
    float* ctxT  = gbT  + 4096 * 64;          // 512*64
    float* combT = ctxT + 512 * 64;           // 512*64
    float* XsT   = combT+ 512 * 64;           // 512*64
    float* P     = XsT  + 512 * 64;           // 8*4096*64
    float* P2    = P    + (size_t)kKS_G * kG4 * kB; // 16*512*64
    float* Pl    = P2   + (size_t)kKS_C * kE * kB;  // 4*64*10000
    float* l     = Pl   + (size_t)kKS_L * kB * kV;  // 64*10000

    k_colsum<<<(kB * kC) / 256, 256, 0, stream>>>(X, XsT);
    k_init2<<<128, 256, 0, stream>>>(XsT, Wc0, bc0, Wh0, bh0, cT, A0);
    k_base2<<<kG4 / 16, 256, 0, stream>>>(XsT, W_ih, b_ih, b_hh, gbT);
    k_ctx2<<<kE / 16, 256, 0, stream>>>(XsT, Wlc, blc, ctxT);
    k_emb0<<<(kE * kB) / 256, 256, 0, stream>>>(emb, A0);
    k_out0<<<(kB * kV + 255) / 256, 256, 0, stream>>>(out);

    float* A[2] = {A0, A1};
    for (int s = 1; s < kT; ++s) {
        const float* Ac = A[(s - 1) & 1];
        float* An = A[s & 1];
        k_gates<<<256 * kKS_G, 256, 0, stream>>>(Ac, W_ih, W_hh, P);
        k_lstm<<<kH / 4, 256, 0, stream>>>(P, gbT, cT, An);
        k_comb<<<32 * kKS_C, 256, 0, stream>>>(An, Wlh, P2);
        k_combred<<<(kE * kB) / 256, 256, 0, stream>>>(P2, Ac, ctxT, blh, combT);
        k_logits<<<625 * kKS_L, 256, 0, stream>>>(combT, Wout, Pl);
        k_lred<<<(kB * kV) / 256, 256, 0, stream>>>(Pl, bout, l);
        k_finish<<<kB, 256, 0, stream>>>(l, out, emb, An, s);
    }
}

// Round 4
// 1512.299 us; speedup vs baseline: 3.9010x; 1.1307x over previous
//
#include <hip/hip_runtime.h>
#include <math.h>

// Problem constants
constexpr int kB = 64;     // batch
constexpr int kN = 196;    // tokens in X
constexpr int kC = 512;    // X channels
constexpr int kE = 512;    // embedding dim
constexpr int kH = 1024;   // hidden
constexpr int kV = 10000;  // vocab
constexpr int kT = 20;     // steps
constexpr int kG4 = 4 * kH; // 4096
constexpr int kKS_G = 8;   // split-K for gates  (K=1536 -> 192 each)
constexpr int kKS_C = 16;  // split-K for comb   (K=1024 -> 64 each)
constexpr int kKS_L = 4;   // split-K for logits (K=512 -> 128 each)
constexpr int kLT = 313;   // logits col-tiles of 32 (313*32 = 10016, last partial)

__device__ __forceinline__ float sigmoidf_(float x) { return 1.0f / (1.0f + expf(-x)); }

// ---------------- setup kernels (run once) ----------------

// 4-way n-split partial colsum: XsP[ch][b][c] = sum_{n in chunk} X[b][n][c]
__global__ __launch_bounds__(256) void k_colsum(const float* __restrict__ X,
                                                float* __restrict__ XsP) {
    int gid = blockIdx.x * 256 + threadIdx.x;    // 4*64*512
    int c = gid & 511, b = (gid >> 9) & 63, ch = gid >> 15;
    const float* p = X + (size_t)b * kN * kC + (size_t)(ch * 49) * kC + c;
    float s = 0.f;
    for (int n = 0; n < 49; ++n) s += p[(size_t)n * kC];
    XsP[gid] = s;
}

// XsT[c][b] = sum_ch XsP[ch][b][c]
__global__ __launch_bounds__(256) void k_colred(const float* __restrict__ XsP,
                                                float* __restrict__ XsT) {
    int gid = blockIdx.x * 256 + threadIdx.x;    // 64*512
    int b = gid >> 9, c = gid & 511;
    float s = 0.f;
#pragma unroll
    for (int ch = 0; ch < 4; ++ch) s += XsP[ch * 32768 + b * 512 + c];
    XsT[c * kB + b] = s;
}

// Unified setup GEMM from XsT (K=512). Col space:
//  tiles [0,128): gbT (W_ih rows 512.., bias b_ih+b_hh)      -> gbT[j][b]
//  tiles [128,160): c0 = tanh(mean@Wc0+bc0)                  -> cT[j][b]
//  tiles [160,192): h0 = tanh(mean@Wh0+bh0)                  -> A0 h-part
//  tiles [192,208): ctx = mean-sum@Wlc+blc                   -> ctxT[j][b]
__global__ __launch_bounds__(256) void k_setupgemm(const float* __restrict__ XsT,
                                                   const float* __restrict__ W_ih,
                                                   const float* __restrict__ b_ih,
                                                   const float* __restrict__ b_hh,
                                                   const float* __restrict__ Wc0,
                                                   const float* __restrict__ bc0,
                                                   const float* __restrict__ Wh0,
                                                   const float* __restrict__ bh0,
                                                   const float* __restrict__ Wlc,
                                                   const float* __restrict__ blc,
                                                   float* __restrict__ gbT,
                                                   float* __restrict__ cT,
                                                   float* __restrict__ A0,
                                                   float* __restrict__ ctxT) {
    __shared__ float4 wt4[64][8];
    int t = threadIdx.x;
    int b = t & 63, q = t >> 6;
    int tile = blockIdx.x;

    const float* W; const float* bias; float* outp; float scale; int ldw; int post;
    int j;
    if (tile < 128) {
        j = tile * 32; W = W_ih + (size_t)kE * kG4 + j; ldw = kG4;
        bias = nullptr; outp = gbT + (size_t)j * kB; scale = 1.f; post = 0;
    } else if (tile < 160) {
        j = (tile - 128) * 32; W = Wc0 + j; ldw = kH;
        bias = bc0 + j; outp = cT + (size_t)j * kB; scale = 1.0f / 196.0f; post = 1;
    } else if (tile < 192) {
        j = (tile - 160) * 32; W = Wh0 + j; ldw = kH;
        bias = bh0 + j; outp = A0 + (size_t)(kE + j) * kB; scale = 1.0f / 196.0f; post = 1;
    } else {
        j = (tile - 192) * 32; W = Wlc + j; ldw = kE;
        bias = blc + j; outp = ctxT + (size_t)j * kB; scale = 1.f; post = 0;
    }

    int lr = t >> 2, lq2 = (t & 3) * 2;
    float acc[8];
#pragma unroll
    for (int i = 0; i < 8; ++i) acc[i] = 0.f;

    for (int kt = 0; kt < kC; kt += 64) {
        const float* wrow = W + (size_t)(kt + lr) * ldw;
        float4 w0 = *reinterpret_cast<const float4*>(wrow + lq2 * 4);
        float4 w1 = *reinterpret_cast<const float4*>(wrow + lq2 * 4 + 4);
        __syncthreads();
        wt4[lr][lq2] = w0; wt4[lr][lq2 + 1] = w1;
        __syncthreads();
        const float* ap = XsT + (size_t)kt * kB + b;
#pragma unroll 8
        for (int kk = 0; kk < 64; ++kk) {
            float a = ap[kk * 64] * scale;
            float4 u0 = wt4[kk][q * 2];
            float4 u1 = wt4[kk][q * 2 + 1];
            acc[0] += a * u0.x; acc[1] += a * u0.y; acc[2] += a * u0.z; acc[3] += a * u0.w;
            acc[4] += a * u1.x; acc[5] += a * u1.y; acc[6] += a * u1.z; acc[7] += a * u1.w;
        }
    }
#pragma unroll
    for (int cc = 0; cc < 8; ++cc) {
        int col = q * 8 + cc;
        float v = acc[cc];
        if (tile < 128) v += b_ih[j + col] + b_hh[j + col];
        else v += bias[col];
        if (post) v = tanhf(v);
        outp[(size_t)col * kB + b] = v;
    }
}

// A0 e-part: emb[START_IDX=1] broadcast to all b
__global__ __launch_bounds__(256) void k_emb0(const float* __restrict__ emb,
                                              float* __restrict__ A0) {
    int gid = blockIdx.x * 256 + threadIdx.x;      // 512*64
    int k = gid >> 6;
    A0[gid] = emb[kE + k];  // row 1
}

// out[:,0,:] = one_hot(1)
__global__ __launch_bounds__(256) void k_out0(float* __restrict__ out) {
    int gid = blockIdx.x * 256 + threadIdx.x;      // 64*10000
    if (gid >= kB * kV) return;
    int b = gid / kV, v = gid - b * kV;
    out[(size_t)b * kT * kV + v] = (v == 1) ? 1.0f : 0.0f;
}

// ---------------- per-step kernels ----------------

// gates partial GEMM: 32-col tiles, LDS-staged weights.
// grid 1024 = 128 col-tiles x 8 k-chunks (192 rows = 3 sub-tiles of 64)
__global__ __launch_bounds__(256) void k_gates(const float* __restrict__ A,
                                               const float* __restrict__ W_ih,
                                               const float* __restrict__ W_hh,
                                               float* __restrict__ P) {
    __shared__ float4 wt4[64][8];   // 8 KB: [k_local][col_quad]
    int t = threadIdx.x;
    int b = t & 63, q = t >> 6;
    int jt = blockIdx.x & 127;
    int kc = blockIdx.x >> 7;
    int j0 = jt * 32;
    int k0 = kc * 192;
    int lr = t >> 2, lq2 = (t & 3) * 2;

    float acc[8];
#pragma unroll
    for (int i = 0; i < 8; ++i) acc[i] = 0.f;

    for (int kt = 0; kt < 192; kt += 64) {
        int k = k0 + kt + lr;
        const float* wrow = (k < kE) ? (W_ih + (size_t)k * kG4)
                                     : (W_hh + (size_t)(k - kE) * kG4);
        float4 w0 = *reinterpret_cast<const float4*>(wrow + j0 + lq2 * 4);
        float4 w1 = *reinterpret_cast<const float4*>(wrow + j0 + lq2 * 4 + 4);
        __syncthreads();
        wt4[lr][lq2] = w0; wt4[lr][lq2 + 1] = w1;
        __syncthreads();
        const float* ap = A + (size_t)(k0 + kt) * kB + b;
#pragma unroll 8
        for (int kk = 0; kk < 64; ++kk) {
            float a = ap[kk * 64];
            float4 u0 = wt4[kk][q * 2];
            float4 u1 = wt4[kk][q * 2 + 1];
            acc[0] += a * u0.x; acc[1] += a * u0.y; acc[2] += a * u0.z; acc[3] += a * u0.w;
            acc[4] += a * u1.x; acc[5] += a * u1.y; acc[6] += a * u1.z; acc[7] += a * u1.w;
        }
    }
    float* p = P + ((size_t)kc * kG4 + j0 + q * 8) * kB + b;
#pragma unroll
    for (int cc = 0; cc < 8; ++cc) p[cc * 64] = acc[cc];
}

// reduce gate partials + gbT, LSTM nonlinearity. grid 256.
__global__ __launch_bounds__(256) void k_lstm(const float* __restrict__ P,
                                              const float* __restrict__ gbT,
                                              float* __restrict__ cT,
                                              float* __restrict__ An) {
    int t = threadIdx.x;
    int b = t & 63, q = t >> 6;
    int j = blockIdx.x * 4 + q;
    float g[4];
#pragma unroll
    for (int gi = 0; gi < 4; ++gi) {
        int row = gi * kH + j;
        float s = gbT[(size_t)row * kB + b];
#pragma unroll
        for (int kc = 0; kc < kKS_G; ++kc)
            s += P[(size_t)kc * kG4 * kB + (size_t)row * kB + b];
        g[gi] = s;
    }
    float c2 = sigmoidf_(g[1]) * cT[j * kB + b] + sigmoidf_(g[0]) * tanhf(g[2]);
    float h2 = sigmoidf_(g[3]) * tanhf(c2);
    cT[j * kB + b] = c2;
    An[(size_t)(kE + j) * kB + b] = h2;
}

// comb partial GEMM. grid 256 = 16 col-tiles x 16 k-chunks (64 rows = 1 sub-tile)
__global__ __launch_bounds__(256) void k_comb(const float* __restrict__ An,
                                              const float* __restrict__ Wlh,
                                              float* __restrict__ P2) {
    __shared__ float4 wt4[64][8];
    int t = threadIdx.x;
    int b = t & 63, q = t >> 6;
    int jt = blockIdx.x & 15;
    int kc = blockIdx.x >> 4;
    int j0 = jt * 32;
    int k0 = kc * 64;
    int lr = t >> 2, lq2 = (t & 3) * 2;

    const float* wrow = Wlh + (size_t)(k0 + lr) * kE + j0;
    float4 w0 = *reinterpret_cast<const float4*>(wrow + lq2 * 4);
    float4 w1 = *reinterpret_cast<const float4*>(wrow + lq2 * 4 + 4);
    wt4[lr][lq2] = w0; wt4[lr][lq2 + 1] = w1;
    __syncthreads();

    float acc[8];
#pragma unroll
    for (int i = 0; i < 8; ++i) acc[i] = 0.f;
    const float* ap = An + (size_t)(kE + k0) * kB + b;
#pragma unroll 8
    for (int kk = 0; kk < 64; ++kk) {
        float a = ap[kk * 64];
        float4 u0 = wt4[kk][q * 2];
        float4 u1 = wt4[kk][q * 2 + 1];
        acc[0] += a * u0.x; acc[1] += a * u0.y; acc[2] += a * u0.z; acc[3] += a * u0.w;
        acc[4] += a * u1.x; acc[5] += a * u1.y; acc[6] += a * u1.z; acc[7] += a * u1.w;
    }
    float* p = P2 + ((size_t)kc * kE + j0 + q * 8) * kB + b;
#pragma unroll
    for (int cc = 0; cc < 8; ++cc) p[cc * 64] = acc[cc];
}

// combT = e + ctx_proj + blh + sum partials. grid 128.
__global__ __launch_bounds__(256) void k_combred(const float* __restrict__ P2,
                                                 const float* __restrict__ Ac,
                                                 const float* __restrict__ ctxT,
                                                 const float* __restrict__ blh,
                                                 float* __restrict__ combT) {
    int gid = blockIdx.x * 256 + threadIdx.x;     // 512*64
    int e = gid >> 6;
    float s = Ac[gid] + ctxT[gid] + blh[e];
#pragma unroll
    for (int kc = 0; kc < kKS_C; ++kc)
        s += P2[(size_t)kc * kE * kB + gid];
    combT[gid] = s;
}

// logits partial GEMM: Pl[kc][b][c]. grid 1252 = 313 col-tiles x 4 k-chunks
__global__ __launch_bounds__(256) void k_logits(const float* __restrict__ combT,
                                                const float* __restrict__ Wout,
                                                float* __restrict__ Pl) {
    __shared__ float4 wt4[64][8];
    int t = threadIdx.x;
    int b = t & 63, q = t >> 6;
    int jt = blockIdx.x % kLT;
    int kc = blockIdx.x / kLT;
    int j0 = jt * 32;
    int k0 = kc * 128;
    int lr = t >> 2, lq2 = (t & 3) * 2;

    float acc[8];
#pragma unroll
    for (int i = 0; i < 8; ++i) acc[i] = 0.f;

    for (int kt = 0; kt < 128; kt += 64) {
        const float* wrow = Wout + (size_t)(k0 + kt + lr) * kV;
        int c0 = j0 + lq2 * 4;
        float4 w0 = (c0 + 3 < kV) ? *reinterpret_cast<const float4*>(wrow + c0)
                                  : make_float4(0.f, 0.f, 0.f, 0.f);
        float4 w1 = (c0 + 7 < kV) ? *reinterpret_cast<const float4*>(wrow + c0 + 4)
                                  : make_float4(0.f, 0.f, 0.f, 0.f);
        __syncthreads();
        wt4[lr][lq2] = w0; wt4[lr][lq2 + 1] = w1;
        __syncthreads();
        const float* ap = combT + (size_t)(k0 + kt) * kB + b;
#pragma unroll 8
        for (int kk = 0; kk < 64; ++kk) {
            float a = ap[kk * 64];
            float4 u0 = wt4[kk][q * 2];
            float4 u1 = wt4[kk][q * 2 + 1];
            acc[0] += a * u0.x; acc[1] += a * u0.y; acc[2] += a * u0.z; acc[3] += a * u0.w;
            acc[4] += a * u1.x; acc[5] += a * u1.y; acc[6] += a * u1.z; acc[7] += a * u1.w;
        }
    }
    float* p = Pl + ((size_t)kc * kB + b) * kV + j0 + q * 8;
#pragma unroll
    for (int cc = 0; cc < 8; ++cc) {
        int col = j0 + q * 8 + cc;
        if (col < kV) p[cc] = acc[cc];
    }
}

// fused: reduce logits partials (+bout) into LDS row, log-softmax, argmax,
// write out row, gather next-step embedding. grid 64.
__global__ __launch_bounds__(256) void k_finish(const float* __restrict__ Pl,
                                                const float* __restrict__ bout,
                                                float* __restrict__ out,
                                                const float* __restrict__ emb,
                                                float* __restrict__ An,
                                                int step) {
    __shared__ float lrow[kV];
    __shared__ float smax[256];
    __shared__ int sidx[256];
    __shared__ float ssum[256];
    int b = blockIdx.x;
    int t = threadIdx.x;

    float mx = -3.4e38f; int mi = 0;
    for (int c = t; c < kV; c += 256) {
        float s = bout[c];
#pragma unroll
        for (int kc = 0; kc < kKS_L; ++kc)
            s += Pl[((size_t)kc * kB + b) * kV + c];
        lrow[c] = s;
        if (s > mx) { mx = s; mi = c; }
    }
    smax[t] = mx; sidx[t] = mi;
    __syncthreads();
    for (int s = 128; s > 0; s >>= 1) {
        if (t < s) {
            float v2 = smax[t + s]; int i2 = sidx[t + s];
            if (v2 > smax[t] || (v2 == smax[t] && i2 < sidx[t])) { smax[t] = v2; sidx[t] = i2; }
        }
        __syncthreads();
    }
    mx = smax[0]; mi = sidx[0];

    float s = 0.f;
    for (int c = t; c < kV; c += 256) s += expf(lrow[c] - mx);
    ssum[t] = s;
    __syncthreads();
    for (int ss = 128; ss > 0; ss >>= 1) {
        if (t < ss) ssum[t] += ssum[t + ss];
        __syncthreads();
    }
    float lse = mx + logf(ssum[0]);

    float* orow = out + (size_t)b * kT * kV + (size_t)step * kV;
    for (int c = t; c < kV; c += 256) orow[c] = lrow[c] - lse;

    for (int k = t; k < kE; k += 256) An[k * kB + b] = emb[(size_t)mi * kE + k];
}

// ---------------- launcher ----------------

extern "C" void kernel_launch(void* const* d_in, const int* in_sizes, int n_in,
                              void* d_out, int out_size, void* d_ws, size_t ws_size,
                              hipStream_t stream) {
    const float* X    = (const float*)d_in[0];
    const float* emb  = (const float*)d_in[1];
    const float* W_ih = (const float*)d_in[2];
    const float* b_ih = (const float*)d_in[3];
    const float* W_hh = (const float*)d_in[4];
    const float* b_hh = (const float*)d_in[5];
    // d_in[6..11]: Wa, ba, Wh, bh, Wo, bo — dead (softmax over size-1 axis => weights==1)
    const float* Wlh  = (const float*)d_in[12];
    const float* blh  = (const float*)d_in[13];
    const float* Wlc  = (const float*)d_in[14];
    const float* blc  = (const float*)d_in[15];
    const float* Wout = (const float*)d_in[16];
    const float* bout = (const float*)d_in[17];
    const float* Wc0  = (const float*)d_in[18];
    const float* bc0  = (const float*)d_in[19];
    const float* Wh0  = (const float*)d_in[20];
    const float* bh0  = (const float*)d_in[21];
    float* out = (float*)d_out;

    float* ws = (float*)d_ws;
    float* A0    = ws;                        // 1536*64
    float* A1    = A0   + 1536 * 64;
    float* cT    = A1   + 1536 * 64;          // 1024*64
    float* gbT   = cT   + 1024 * 64;          // 4096*64
    float* ctxT  = gbT  + 4096 * 64;          // 512*64
    float* combT = ctxT + 512 * 64;           // 512*64
    float* XsT   = combT+ 512 * 64;           // 512*64
    float* XsP   = XsT  + 512 * 64;           // 4*64*512
    float* P     = XsP  + 4 * 64 * 512;       // 8*4096*64
    float* P2    = P    + (size_t)kKS_G * kG4 * kB; // 16*512*64
    float* Pl    = P2   + (size_t)kKS_C * kE * kB;  // 4*64*10000

    k_colsum<<<512, 256, 0, stream>>>(X, XsP);
    k_colred<<<128, 256, 0, stream>>>(XsP, XsT);
    k_setupgemm<<<208, 256, 0, stream>>>(XsT, W_ih, b_ih, b_hh, Wc0, bc0,
                                         Wh0, bh0, Wlc, blc, gbT, cT, A0, ctxT);
    k_emb0<<<(kE * kB) / 256, 256, 0, stream>>>(emb, A0);
    k_out0<<<(kB * kV + 255) / 256, 256, 0, stream>>>(out);

    float* A[2] = {A0, A1};
    for (int s = 1; s < kT; ++s) {
        const float* Ac = A[(s - 1) & 1];
        float* An = A[s & 1];
        k_gates<<<128 * kKS_G, 256, 0, stream>>>(Ac, W_ih, W_hh, P);
        k_lstm<<<kH / 4, 256, 0, stream>>>(P, gbT, cT, An);
        k_comb<<<16 * kKS_C, 256, 0, stream>>>(An, Wlh, P2);
        k_combred<<<(kE * kB) / 256, 256, 0, stream>>>(P2, Ac, ctxT, blh, combT);
        k_logits<<<kLT * kKS_L, 256, 0, stream>>>(combT, Wout, Pl);
        k_finish<<<kB, 256, 0, stream>>>(Pl, bout, out, emb, An, s);
    }
}

// Round 6
// 1403.385 us; speedup vs baseline: 4.2038x; 1.0776x over previous
//
#include <hip/hip_runtime.h>
#include <math.h>

typedef unsigned short u16;
typedef __attribute__((ext_vector_type(8))) short bf16x8;
typedef __attribute__((ext_vector_type(4))) float f32x4;
typedef __attribute__((ext_vector_type(8))) unsigned short ushort8;

// Problem constants
constexpr int kB = 64;     // batch
constexpr int kN = 196;    // tokens in X
constexpr int kC = 512;    // X channels
constexpr int kE = 512;    // embedding dim
constexpr int kH = 1024;   // hidden
constexpr int kV = 10000;  // vocab
constexpr int kVP = 10048; // vocab padded to 157*64
constexpr int kT = 20;     // steps
constexpr int kG4 = 4 * kH;   // 4096
constexpr int kKA = 1536;     // activation K (e|h)
constexpr int kKS_G = 6;      // gates split-K (256 k each)
constexpr int kKS_C = 16;     // comb split-K (64 k each)
constexpr int kKS_L = 2;      // logits split-K (256 k each)

__device__ __forceinline__ float sigmoidf_(float x) { return 1.0f / (1.0f + expf(-x)); }

// bf16 RNE convert + exact widen (bf16->f32 is a shift)
__device__ __forceinline__ u16 f2bf(float x) {
    unsigned u = __float_as_uint(x);
    u += 0x7FFF + ((u >> 16) & 1);
    return (u16)(u >> 16);
}
__device__ __forceinline__ float bf2f(u16 u) {
    return __uint_as_float((unsigned)u << 16);
}
__device__ __forceinline__ void splitbf(float x, u16& hi, u16& lo) {
    hi = f2bf(x);
    lo = f2bf(x - bf2f(hi));
}

// ---------------- setup kernels (run once) ----------------

// 4-way n-split partial colsum: XsP[ch][b][c] = sum_{n in chunk} X[b][n][c]
__global__ __launch_bounds__(256) void k_colsum(const float* __restrict__ X,
                                                float* __restrict__ XsP) {
    int gid = blockIdx.x * 256 + threadIdx.x;    // 4*64*512
    int c = gid & 511, b = (gid >> 9) & 63, ch = gid >> 15;
    const float* p = X + (size_t)b * kN * kC + (size_t)(ch * 49) * kC + c;
    float s = 0.f;
    for (int n = 0; n < 49; ++n) s += p[(size_t)n * kC];
    XsP[gid] = s;
}

// XsT[c][b] = sum_ch XsP[ch][b][c]
__global__ __launch_bounds__(256) void k_colred(const float* __restrict__ XsP,
                                                float* __restrict__ XsT) {
    int gid = blockIdx.x * 256 + threadIdx.x;    // 64*512
    int b = gid >> 9, c = gid & 511;
    float s = 0.f;
#pragma unroll
    for (int ch = 0; ch < 4; ++ch) s += XsP[ch * 32768 + b * 512 + c];
    XsT[c * kB + b] = s;
}

// Unified fp32 setup GEMM from XsT (K=512); outputs in b-major layouts.
//  tiles [0,128): gbBJ[b][j] = b_ih+b_hh+Xsum@W_ih[512..]
//  tiles [128,160): cBJ[b][j] = tanh(mean@Wc0+bc0)
//  tiles [160,192): h0 -> Ab0 hi/lo [b][512+j]
//  tiles [192,208): ctxBJ[b][e] = Xsum@Wlc+blc
__global__ __launch_bounds__(256) void k_setupgemm(const float* __restrict__ XsT,
                                                   const float* __restrict__ W_ih,
                                                   const float* __restrict__ b_ih,
                                                   const float* __restrict__ b_hh,
                                                   const float* __restrict__ Wc0,
                                                   const float* __restrict__ bc0,
                                                   const float* __restrict__ Wh0,
                                                   const float* __restrict__ bh0,
                                                   const float* __restrict__ Wlc,
                                                   const float* __restrict__ blc,
                                                   float* __restrict__ gbBJ,
                                                   float* __restrict__ cBJ,
                                                   u16* __restrict__ Ab0Hi,
                                                   u16* __restrict__ Ab0Lo,
                                                   float* __restrict__ ctxBJ) {
    __shared__ float4 wt4[64][8];
    int t = threadIdx.x;
    int b = t & 63, q = t >> 6;
    int tile = blockIdx.x;

    const float* W; const float* bias; float scale; int ldw; int mode; int j;
    if (tile < 128) {
        j = tile * 32; W = W_ih + (size_t)kE * kG4 + j; ldw = kG4;
        bias = nullptr; scale = 1.f; mode = 0;
    } else if (tile < 160) {
        j = (tile - 128) * 32; W = Wc0 + j; ldw = kH;
        bias = bc0 + j; scale = 1.0f / 196.0f; mode = 1;
    } else if (tile < 192) {
        j = (tile - 160) * 32; W = Wh0 + j; ldw = kH;
        bias = bh0 + j; scale = 1.0f / 196.0f; mode = 2;
    } else {
        j = (tile - 192) * 32; W = Wlc + j; ldw = kE;
        bias = blc + j; scale = 1.f; mode = 3;
    }

    int lr = t >> 2, lq2 = (t & 3) * 2;
    float acc[8];
#pragma unroll
    for (int i = 0; i < 8; ++i) acc[i] = 0.f;

    for (int kt = 0; kt < kC; kt += 64) {
        const float* wrow = W + (size_t)(kt + lr) * ldw;
        float4 w0 = *reinterpret_cast<const float4*>(wrow + lq2 * 4);
        float4 w1 = *reinterpret_cast<const float4*>(wrow + lq2 * 4 + 4);
        __syncthreads();
        wt4[lr][lq2] = w0; wt4[lr][lq2 + 1] = w1;
        __syncthreads();
        const float* ap = XsT + (size_t)kt * kB + b;
#pragma unroll 8
        for (int kk = 0; kk < 64; ++kk) {
            float a = ap[kk * 64] * scale;
            float4 u0 = wt4[kk][q * 2];
            float4 u1 = wt4[kk][q * 2 + 1];
            acc[0] += a * u0.x; acc[1] += a * u0.y; acc[2] += a * u0.z; acc[3] += a * u0.w;
            acc[4] += a * u1.x; acc[5] += a * u1.y; acc[6] += a * u1.z; acc[7] += a * u1.w;
        }
    }
#pragma unroll
    for (int cc = 0; cc < 8; ++cc) {
        int col = q * 8 + cc;
        float v = acc[cc];
        if (mode == 0) {
            v += b_ih[j + col] + b_hh[j + col];
            gbBJ[(size_t)b * kG4 + j + col] = v;
        } else if (mode == 1) {
            v = tanhf(v + bias[col]);
            cBJ[(size_t)b * kH + j + col] = v;
        } else if (mode == 2) {
            v = tanhf(v + bias[col]);
            u16 hi, lo; splitbf(v, hi, lo);
            Ab0Hi[(size_t)b * kKA + kE + j + col] = hi;
            Ab0Lo[(size_t)b * kKA + kE + j + col] = lo;
        } else {
            v += bias[col];
            ctxBJ[(size_t)b * kE + j + col] = v;
        }
    }
}

// transpose + bf16 hi/lo split of a weight matrix: dst[n][k] from src[k][n]
// grid = nxTiles * kyTiles; block tile 64(k) x 64(n)
__global__ __launch_bounds__(256) void k_wconv(const float* __restrict__ src,
                                               u16* __restrict__ dhi,
                                               u16* __restrict__ dlo,
                                               int ld, int n_valid, int pitch,
                                               int k_off, int nxTiles) {
    __shared__ float lds[64][65];
    int t = threadIdx.x;
    int nx = blockIdx.x % nxTiles, ky = blockIdx.x / nxTiles;
    int n0 = nx * 64, k0 = ky * 64;
    int c = t & 63, r0 = t >> 6;
#pragma unroll
    for (int i = 0; i < 16; ++i) {
        int r = r0 + i * 4;
        float v = (n0 + c < n_valid) ? src[(size_t)(k0 + r) * ld + n0 + c] : 0.f;
        lds[r][c] = v;
    }
    __syncthreads();
    // FIX (round 5): cover ALL 64 k per tile. Each thread writes 16 k-values
    // (2x ushort8): k_local = kq*16 + half*8 + jj, kq in [0,4) -> [0,64).
    int nl = t >> 2, kq = t & 3;
#pragma unroll
    for (int half = 0; half < 2; ++half) {
        ushort8 vh, vl;
#pragma unroll
        for (int jj = 0; jj < 8; ++jj) {
            float v = lds[kq * 16 + half * 8 + jj][nl];
            u16 hi, lo; splitbf(v, hi, lo);
            vh[jj] = hi; vl[jj] = lo;
        }
        size_t o = (size_t)(n0 + nl) * pitch + k_off + k0 + kq * 16 + half * 8;
        *(ushort8*)(&dhi[o]) = vh;
        *(ushort8*)(&dlo[o]) = vl;
    }
}

// Ab0 e-part: emb[START_IDX=1] broadcast to all b (bf16 split)
__global__ __launch_bounds__(256) void k_emb0(const float* __restrict__ emb,
                                              u16* __restrict__ AbHi,
                                              u16* __restrict__ AbLo) {
    int gid = blockIdx.x * 256 + threadIdx.x;      // 64*512
    int b = gid >> 9, k = gid & 511;
    u16 hi, lo; splitbf(emb[kE + k], hi, lo);
    AbHi[(size_t)b * kKA + k] = hi;
    AbLo[(size_t)b * kKA + k] = lo;
}

// out[:,0,:] = one_hot(1)
__global__ __launch_bounds__(256) void k_out0(float* __restrict__ out) {
    int gid = blockIdx.x * 256 + threadIdx.x;      // 64*10000
    if (gid >= kB * kV) return;
    int b = gid / kV, v = gid - b * kV;
    out[(size_t)b * kT * kV + v] = (v == 1) ? 1.0f : 0.0f;
}

// ---------------- per-step MFMA GEMMs (bf16x3 split precision) ----------------
// A-frag (activations, M=batch): lane la=l&15 -> batch row, lg=l>>4 -> k-group.
// B-frag (weights from LDS, N-cols): la -> n col, lg -> k-group.
// D: col = la (n), row = lg*4+r (batch within M-tile).  [m89-verified layout]

// gates: M=64, N=4096, K=1536. grid 64 n-blocks x 6 kc = 384.
__global__ __launch_bounds__(256) void k_mgates(const u16* __restrict__ AbHi,
                                                const u16* __restrict__ AbLo,
                                                const u16* __restrict__ WHi,
                                                const u16* __restrict__ WLo,
                                                float* __restrict__ P) {
    __shared__ u16 sHi[64 * 40], sLo[64 * 40];
    int t = threadIdx.x;
    int l = t & 63, w = t >> 6;
    int nb = blockIdx.x & 63, kc = blockIdx.x >> 6;
    int n0 = nb * 64, kbase = kc * 256;
    int srow = t >> 2, squad = t & 3;
    const u16* gHi = WHi + (size_t)(n0 + srow) * kKA + kbase + squad * 8;
    const u16* gLo = WLo + (size_t)(n0 + srow) * kKA + kbase + squad * 8;
    int la = l & 15, lg = l >> 4;

    f32x4 acc[4];
#pragma unroll
    for (int m = 0; m < 4; ++m) acc[m] = (f32x4){0.f, 0.f, 0.f, 0.f};

    for (int ks = 0; ks < 8; ++ks) {
        ushort8 th = *(const ushort8*)(gHi + ks * 32);
        ushort8 tl = *(const ushort8*)(gLo + ks * 32);
        __syncthreads();
        *(ushort8*)(&sHi[srow * 40 + squad * 8]) = th;
        *(ushort8*)(&sLo[srow * 40 + squad * 8]) = tl;
        __syncthreads();
        bf16x8 whi = *(const bf16x8*)(&sHi[(w * 16 + la) * 40 + lg * 8]);
        bf16x8 wlo = *(const bf16x8*)(&sLo[(w * 16 + la) * 40 + lg * 8]);
        int kg = kbase + ks * 32 + lg * 8;
#pragma unroll
        for (int m = 0; m < 4; ++m) {
            bf16x8 ahi = *(const bf16x8*)(AbHi + (size_t)(m * 16 + la) * kKA + kg);
            bf16x8 alo = *(const bf16x8*)(AbLo + (size_t)(m * 16 + la) * kKA + kg);
            acc[m] = __builtin_amdgcn_mfma_f32_16x16x32_bf16(ahi, whi, acc[m], 0, 0, 0);
            acc[m] = __builtin_amdgcn_mfma_f32_16x16x32_bf16(ahi, wlo, acc[m], 0, 0, 0);
            acc[m] = __builtin_amdgcn_mfma_f32_16x16x32_bf16(alo, whi, acc[m], 0, 0, 0);
        }
    }
    int n = n0 + w * 16 + la;
    float* base = P + (size_t)kc * 64 * kG4 + n;
#pragma unroll
    for (int m = 0; m < 4; ++m)
#pragma unroll
        for (int r = 0; r < 4; ++r)
            base[(size_t)(m * 16 + lg * 4 + r) * kG4] = acc[m][r];
}

// comb: M=64, N=512, K=1024 (Ab h-part). grid 8 n-blocks x 16 kc = 128.
__global__ __launch_bounds__(256) void k_mcomb(const u16* __restrict__ AbHi,
                                               const u16* __restrict__ AbLo,
                                               const u16* __restrict__ WHi,
                                               const u16* __restrict__ WLo,
                                               float* __restrict__ P2) {
    __shared__ u16 sHi[64 * 40], sLo[64 * 40];
    int t = threadIdx.x;
    int l = t & 63, w = t >> 6;
    int nb = blockIdx.x & 7, kc = blockIdx.x >> 3;
    int n0 = nb * 64, kw = kc * 64;   // weight-k base (h index)
    int srow = t >> 2, squad = t & 3;
    const u16* gHi = WHi + (size_t)(n0 + srow) * kH + kw + squad * 8;
    const u16* gLo = WLo + (size_t)(n0 + srow) * kH + kw + squad * 8;
    int la = l & 15, lg = l >> 4;

    f32x4 acc[4];
#pragma unroll
    for (int m = 0; m < 4; ++m) acc[m] = (f32x4){0.f, 0.f, 0.f, 0.f};

    for (int ks = 0; ks < 2; ++ks) {
        ushort8 th = *(const ushort8*)(gHi + ks * 32);
        ushort8 tl = *(const ushort8*)(gLo + ks * 32);
        __syncthreads();
        *(ushort8*)(&sHi[srow * 40 + squad * 8]) = th;
        *(ushort8*)(&sLo[srow * 40 + squad * 8]) = tl;
        __syncthreads();
        bf16x8 whi = *(const bf16x8*)(&sHi[(w * 16 + la) * 40 + lg * 8]);
        bf16x8 wlo = *(const bf16x8*)(&sLo[(w * 16 + la) * 40 + lg * 8]);
        int kg = kE + kw + ks * 32 + lg * 8;   // Ab index
#pragma unroll
        for (int m = 0; m < 4; ++m) {
            bf16x8 ahi = *(const bf16x8*)(AbHi + (size_t)(m * 16 + la) * kKA + kg);
            bf16x8 alo = *(const bf16x8*)(AbLo + (size_t)(m * 16 + la) * kKA + kg);
            acc[m] = __builtin_amdgcn_mfma_f32_16x16x32_bf16(ahi, whi, acc[m], 0, 0, 0);
            acc[m] = __builtin_amdgcn_mfma_f32_16x16x32_bf16(ahi, wlo, acc[m], 0, 0, 0);
            acc[m] = __builtin_amdgcn_mfma_f32_16x16x32_bf16(alo, whi, acc[m], 0, 0, 0);
        }
    }
    int n = n0 + w * 16 + la;
    float* base = P2 + (size_t)kc * 64 * kE + n;
#pragma unroll
    for (int m = 0; m < 4; ++m)
#pragma unroll
        for (int r = 0; r < 4; ++r)
            base[(size_t)(m * 16 + lg * 4 + r) * kE] = acc[m][r];
}

// logits: M=64, N=10048(pad), K=512 (Cb). grid 157 n-blocks x 2 kc = 314.
__global__ __launch_bounds__(256) void k_mlogits(const u16* __restrict__ CbHi,
                                                 const u16* __restrict__ CbLo,
                                                 const u16* __restrict__ WHi,
                                                 const u16* __restrict__ WLo,
                                                 float* __restrict__ Pl) {
    __shared__ u16 sHi[64 * 40], sLo[64 * 40];
    int t = threadIdx.x;
    int l = t & 63, w = t >> 6;
    int nb = blockIdx.x % 157, kc = blockIdx.x / 157;
    int n0 = nb * 64, kbase = kc * 256;
    int srow = t >> 2, squad = t & 3;
    const u16* gHi = WHi + (size_t)(n0 + srow) * kE + kbase + squad * 8;
    const u16* gLo = WLo + (size_t)(n0 + srow) * kE + kbase + squad * 8;
    int la = l & 15, lg = l >> 4;

    f32x4 acc[4];
#pragma unroll
    for (int m = 0; m < 4; ++m) acc[m] = (f32x4){0.f, 0.f, 0.f, 0.f};

    for (int ks = 0; ks < 8; ++ks) {
        ushort8 th = *(const ushort8*)(gHi + ks * 32);
        ushort8 tl = *(const ushort8*)(gLo + ks * 32);
        __syncthreads();
        *(ushort8*)(&sHi[srow * 40 + squad * 8]) = th;
        *(ushort8*)(&sLo[srow * 40 + squad * 8]) = tl;
        __syncthreads();
        bf16x8 whi = *(const bf16x8*)(&sHi[(w * 16 + la) * 40 + lg * 8]);
        bf16x8 wlo = *(const bf16x8*)(&sLo[(w * 16 + la) * 40 + lg * 8]);
        int kg = kbase + ks * 32 + lg * 8;
#pragma unroll
        for (int m = 0; m < 4; ++m) {
            bf16x8 ahi = *(const bf16x8*)(CbHi + (size_t)(m * 16 + la) * kE + kg);
            bf16x8 alo = *(const bf16x8*)(CbLo + (size_t)(m * 16 + la) * kE + kg);
            acc[m] = __builtin_amdgcn_mfma_f32_16x16x32_bf16(ahi, whi, acc[m], 0, 0, 0);
            acc[m] = __builtin_amdgcn_mfma_f32_16x16x32_bf16(ahi, wlo, acc[m], 0, 0, 0);
            acc[m] = __builtin_amdgcn_mfma_f32_16x16x32_bf16(alo, whi, acc[m], 0, 0, 0);
        }
    }
    int n = n0 + w * 16 + la;
    float* base = Pl + (size_t)kc * 64 * kVP + n;
#pragma unroll
    for (int m = 0; m < 4; ++m)
#pragma unroll
        for (int r = 0; r < 4; ++r)
            base[(size_t)(m * 16 + lg * 4 + r) * kVP] = acc[m][r];
}

// reduce gate partials + gbBJ, LSTM nonlinearity -> c, h(bf16 hi/lo). grid 64.
__global__ __launch_bounds__(256) void k_mlstm(const float* __restrict__ P,
                                               const float* __restrict__ gbBJ,
                                               float* __restrict__ cBJ,
                                               u16* __restrict__ AnHi,
                                               u16* __restrict__ AnLo) {
    int t = threadIdx.x;
    int blk = blockIdx.x;
    int j = (blk & 15) * 64 + (t & 63);
    int b0 = (blk >> 4) * 16 + (t >> 6) * 4;
#pragma unroll
    for (int bb = 0; bb < 4; ++bb) {
        int b = b0 + bb;
        float g[4];
#pragma unroll
        for (int gi = 0; gi < 4; ++gi) {
            int col = gi * kH + j;
            float s = gbBJ[(size_t)b * kG4 + col];
#pragma unroll
            for (int kc = 0; kc < kKS_G; ++kc)
                s += P[((size_t)kc * 64 + b) * kG4 + col];
            g[gi] = s;
        }
        float c2 = sigmoidf_(g[1]) * cBJ[b * kH + j] + sigmoidf_(g[0]) * tanhf(g[2]);
        float h2 = sigmoidf_(g[3]) * tanhf(c2);
        cBJ[b * kH + j] = c2;
        u16 hi, lo; splitbf(h2, hi, lo);
        AnHi[(size_t)b * kKA + kE + j] = hi;
        AnLo[(size_t)b * kKA + kE + j] = lo;
    }
}

// comb = e + ctx + blh + sum P2 -> Cb hi/lo. grid 128.
__global__ __launch_bounds__(256) void k_mcombred(const float* __restrict__ P2,
                                                  const u16* __restrict__ AcHi,
                                                  const u16* __restrict__ AcLo,
                                                  const float* __restrict__ ctxBJ,
                                                  const float* __restrict__ blh,
                                                  u16* __restrict__ CbHi,
                                                  u16* __restrict__ CbLo) {
    int t = threadIdx.x;
    int e = (blockIdx.x & 7) * 64 + (t & 63);
    int b = (blockIdx.x >> 3) * 4 + (t >> 6);
    float ev = bf2f(AcHi[(size_t)b * kKA + e]) + bf2f(AcLo[(size_t)b * kKA + e]);
    float s = ev + ctxBJ[(size_t)b * kE + e] + blh[e];
#pragma unroll
    for (int kc = 0; kc < kKS_C; ++kc)
        s += P2[((size_t)kc * 64 + b) * kE + e];
    u16 hi, lo; splitbf(s, hi, lo);
    CbHi[(size_t)b * kE + e] = hi;
    CbLo[(size_t)b * kE + e] = lo;
}

// fused: reduce logits partials+bout, log-softmax, argmax, out row, emb gather. grid 64.
__global__ __launch_bounds__(256) void k_mfinish(const float* __restrict__ Pl,
                                                 const float* __restrict__ bout,
                                                 float* __restrict__ out,
                                                 const float* __restrict__ emb,
                                                 u16* __restrict__ AnHi,
                                                 u16* __restrict__ AnLo,
                                                 int step) {
    __shared__ float lrow[kV];
    __shared__ float smax[256];
    __shared__ int sidx[256];
    __shared__ float ssum[256];
    int b = blockIdx.x;
    int t = threadIdx.x;
    const float* p0 = Pl + (size_t)b * kVP;
    const float* p1 = Pl + (size_t)(64 + b) * kVP;

    float mx = -3.4e38f; int mi = 0;
    for (int c = t; c < kV; c += 256) {
        float s = p0[c] + p1[c] + bout[c];
        lrow[c] = s;
        if (s > mx) { mx = s; mi = c; }
    }
    smax[t] = mx; sidx[t] = mi;
    __syncthreads();
    for (int s = 128; s > 0; s >>= 1) {
        if (t < s) {
            float v2 = smax[t + s]; int i2 = sidx[t + s];
            if (v2 > smax[t] || (v2 == smax[t] && i2 < sidx[t])) { smax[t] = v2; sidx[t] = i2; }
        }
        __syncthreads();
    }
    mx = smax[0]; mi = sidx[0];

    float s = 0.f;
    for (int c = t; c < kV; c += 256) s += expf(lrow[c] - mx);
    ssum[t] = s;
    __syncthreads();
    for (int ss = 128; ss > 0; ss >>= 1) {
        if (t < ss) ssum[t] += ssum[t + ss];
        __syncthreads();
    }
    float lse = mx + logf(ssum[0]);

    float* orow = out + (size_t)b * kT * kV + (size_t)step * kV;
    for (int c = t; c < kV; c += 256) orow[c] = lrow[c] - lse;

    for (int k = t; k < kE; k += 256) {
        u16 hi, lo; splitbf(emb[(size_t)mi * kE + k], hi, lo);
        AnHi[(size_t)b * kKA + k] = hi;
        AnLo[(size_t)b * kKA + k] = lo;
    }
}

// ---------------- launcher ----------------

extern "C" void kernel_launch(void* const* d_in, const int* in_sizes, int n_in,
                              void* d_out, int out_size, void* d_ws, size_t ws_size,
                              hipStream_t stream) {
    const float* X    = (const float*)d_in[0];
    const float* emb  = (const float*)d_in[1];
    const float* W_ih = (const float*)d_in[2];
    const float* b_ih = (const float*)d_in[3];
    const float* W_hh = (const float*)d_in[4];
    const float* b_hh = (const float*)d_in[5];
    // d_in[6..11]: Wa, ba, Wh, bh, Wo, bo — dead (softmax over size-1 axis => weights==1)
    const float* Wlh  = (const float*)d_in[12];
    const float* blh  = (const float*)d_in[13];
    const float* Wlc  = (const float*)d_in[14];
    const float* blc  = (const float*)d_in[15];
    const float* Wout = (const float*)d_in[16];
    const float* bout = (const float*)d_in[17];
    const float* Wc0  = (const float*)d_in[18];
    const float* bc0  = (const float*)d_in[19];
    const float* Wh0  = (const float*)d_in[20];
    const float* bh0  = (const float*)d_in[21];
    float* out = (float*)d_out;

    char* cur = (char*)d_ws;
    auto carve = [&](size_t bytes) { char* p = cur; cur += (bytes + 255) & ~(size_t)255; return p; };

    u16* AbHi0 = (u16*)carve((size_t)kB * kKA * 2);
    u16* AbLo0 = (u16*)carve((size_t)kB * kKA * 2);
    u16* AbHi1 = (u16*)carve((size_t)kB * kKA * 2);
    u16* AbLo1 = (u16*)carve((size_t)kB * kKA * 2);
    float* cBJ   = (float*)carve((size_t)kB * kH * 4);
    float* gbBJ  = (float*)carve((size_t)kB * kG4 * 4);
    float* ctxBJ = (float*)carve((size_t)kB * kE * 4);
    u16* CbHi  = (u16*)carve((size_t)kB * kE * 2);
    u16* CbLo  = (u16*)carve((size_t)kB * kE * 2);
    float* XsT = (float*)carve((size_t)kC * kB * 4);
    float* XsP = (float*)carve((size_t)4 * kB * kC * 4);
    float* P   = (float*)carve((size_t)kKS_G * kB * kG4 * 4);
    float* P2  = (float*)carve((size_t)kKS_C * kB * kE * 4);
    float* Pl  = (float*)carve((size_t)kKS_L * kB * kVP * 4);
    u16* WgHi  = (u16*)carve((size_t)kG4 * kKA * 2);
    u16* WgLo  = (u16*)carve((size_t)kG4 * kKA * 2);
    u16* WlhHi = (u16*)carve((size_t)kE * kH * 2);
    u16* WlhLo = (u16*)carve((size_t)kE * kH * 2);
    u16* WoHi  = (u16*)carve((size_t)kVP * kE * 2);
    u16* WoLo  = (u16*)carve((size_t)kVP * kE * 2);

    // one-time setup
    k_colsum<<<512, 256, 0, stream>>>(X, XsP);
    k_colred<<<128, 256, 0, stream>>>(XsP, XsT);
    k_setupgemm<<<208, 256, 0, stream>>>(XsT, W_ih, b_ih, b_hh, Wc0, bc0,
                                         Wh0, bh0, Wlc, blc, gbBJ, cBJ,
                                         AbHi0, AbLo0, ctxBJ);
    k_emb0<<<128, 256, 0, stream>>>(emb, AbHi0, AbLo0);
    k_out0<<<(kB * kV + 255) / 256, 256, 0, stream>>>(out);
    // weight convert+transpose: WgT[n][k]: k<512 from W_ih rows 0..511, k>=512 from W_hh
    k_wconv<<<64 * 8, 256, 0, stream>>>(W_ih, WgHi, WgLo, kG4, kG4, kKA, 0, 64);
    k_wconv<<<64 * 16, 256, 0, stream>>>(W_hh, WgHi, WgLo, kG4, kG4, kKA, kE, 64);
    k_wconv<<<8 * 16, 256, 0, stream>>>(Wlh, WlhHi, WlhLo, kE, kE, kH, 0, 8);
    k_wconv<<<157 * 8, 256, 0, stream>>>(Wout, WoHi, WoLo, kV, kV, kE, 0, 157);

    u16* AHi[2] = {AbHi0, AbHi1};
    u16* ALo[2] = {AbLo0, AbLo1};
    for (int s = 1; s < kT; ++s) {
        const u16* AcHi = AHi[(s - 1) & 1];
        const u16* AcLo = ALo[(s - 1) & 1];
        u16* AnHi = AHi[s & 1];
        u16* AnLo = ALo[s & 1];
        k_mgates<<<64 * kKS_G, 256, 0, stream>>>(AcHi, AcLo, WgHi, WgLo, P);
        k_mlstm<<<64, 256, 0, stream>>>(P, gbBJ, cBJ, AnHi, AnLo);
        k_mcomb<<<8 * kKS_C, 256, 0, stream>>>(AnHi, AnLo, WlhHi, WlhLo, P2);
        k_mcombred<<<128, 256, 0, stream>>>(P2, AcHi, AcLo, ctxBJ, blh, CbHi, CbLo);
        k_mlogits<<<157 * kKS_L, 256, 0, stream>>>(CbHi, CbLo, WoHi, WoLo, Pl);
        k_mfinish<<<64, 256, 0, stream>>>(Pl, bout, out, emb, AnHi, AnLo, s);
    }
}